// Round 1
// baseline (516.715 us; speedup 1.0000x reference)
//
#include <hip/hip_runtime.h>

// Problem constants (B=8, N=4096, Din=128, Dout=256)
#define TT 16            // tokens per block
#define NTOK 32768       // B*N
#define NBLK (NTOK/TT)   // 2048

__global__ __launch_bounds__(256) void prep_kernel(
    const float* __restrict__ A, const float* __restrict__ Bm,
    const float* __restrict__ C, const float* __restrict__ W,
    float* __restrict__ M3t, float* __restrict__ Wt) {
  int tid = blockIdx.x * 256 + threadIdx.x;
  if (tid < 128 * 256) {
    // M3t[e][f] = (A+B+C)[f][e]
    int f = tid & 255, e = tid >> 8;
    int src = f * 128 + e;
    M3t[tid] = A[src] + Bm[src] + C[src];
  } else {
    int t2 = tid - 128 * 256;
    if (t2 < 256 * 256) {
      // Wt[c][o] = W[o][c]
      int o = t2 & 255, c = t2 >> 8;
      Wt[t2] = W[o * 256 + c];
    }
  }
}

__global__ __launch_bounds__(256) void affine_vnrelu_kernel(
    const float* __restrict__ X, const float* __restrict__ J,
    const float* __restrict__ M3t, const float* __restrict__ Wt,
    float* __restrict__ out) {
  // smem layout: phase A/B: a[e=128][j=48]  (j = i*16 + t)
  //              phase C/D: y[c=256][j=48]
  __shared__ float smem[256 * 48];  // 48 KB
  const int tid = threadIdx.x;
  const long g0 = (long)blockIdx.x * TT;    // first global token of block
  const int b = (int)(g0 >> 12);            // N = 4096
  const int n0 = (int)(g0 & 4095);

  // ---------------- Phase A: Gram-Schmidt + a = R^T X ----------------
  // 2048 (t, channel) pairs, 8 per thread
  #pragma unroll
  for (int k = 0; k < 8; ++k) {
    int p = k * 256 + tid;
    int t = p >> 7;          // token within block
    int dch = p & 127;       // channel
    long gtok = g0 + t;
    const float* Xp = X + (gtok * 128 + dch) * 3;
    const float* Jp = J + (gtok * 128 + dch) * 6;
    float x0 = Xp[0], x1 = Xp[1], x2 = Xp[2];
    float j0 = Jp[0], j1 = Jp[1], j2 = Jp[2], j3 = Jp[3], j4 = Jp[4], j5 = Jp[5];
    // columns of the 3x2: col0 = (j0,j2,j4), col1 = (j1,j3,j5)
    float c00 = j0, c01 = j2, c02 = j4;
    float a20 = j1, a21 = j3, a22 = j5;
    float n1 = sqrtf(c00 * c00 + c01 * c01 + c02 * c02);
    float inv1 = 1.0f / fmaxf(n1, 1e-12f);
    float b10 = c00 * inv1, b11 = c01 * inv1, b12 = c02 * inv1;
    float pr = b10 * a20 + b11 * a21 + b12 * a22;
    float u0 = a20 - pr * b10, u1 = a21 - pr * b11, u2 = a22 - pr * b12;
    float n2 = sqrtf(u0 * u0 + u1 * u1 + u2 * u2);
    float inv2 = 1.0f / fmaxf(n2, 1e-12f);
    float b20 = u0 * inv2, b21 = u1 * inv2, b22 = u2 * inv2;
    float b30 = b11 * b22 - b12 * b21;
    float b31 = b12 * b20 - b10 * b22;
    float b32 = b10 * b21 - b11 * b20;
    float a0 = b10 * x0 + b11 * x1 + b12 * x2;
    float a1 = b20 * x0 + b21 * x1 + b22 * x2;
    float a2 = b30 * x0 + b31 * x1 + b32 * x2;
    float* ar = smem + dch * 48;
    ar[t]      = a0;
    ar[16 + t] = a1;
    ar[32 + t] = a2;
  }
  __syncthreads();

  // ---------------- Phase B: Y[f=tid][j] = sum_e M3t[e][f] * a[e][j] ----------------
  float acc[48];
  #pragma unroll
  for (int q = 0; q < 48; ++q) acc[q] = 0.0f;
  for (int e = 0; e < 128; ++e) {
    float m = M3t[e * 256 + tid];
    const float4* ar = (const float4*)(smem + e * 48);
    #pragma unroll
    for (int q = 0; q < 12; ++q) {
      float4 v = ar[q];
      acc[4 * q + 0] += m * v.x;
      acc[4 * q + 1] += m * v.y;
      acc[4 * q + 2] += m * v.z;
      acc[4 * q + 3] += m * v.w;
    }
  }
  __syncthreads();

  // stash Y into LDS: y[c=tid][j]
  {
    float4* yw = (float4*)(smem + tid * 48);
    #pragma unroll
    for (int q = 0; q < 12; ++q)
      yw[q] = make_float4(acc[4 * q + 0], acc[4 * q + 1], acc[4 * q + 2], acc[4 * q + 3]);
  }
  __syncthreads();

  // ---------------- Phase C: d[o=tid][j] = sum_c Wt[c][o] * y[c][j] ----------------
  #pragma unroll
  for (int q = 0; q < 48; ++q) acc[q] = 0.0f;
  for (int c = 0; c < 256; ++c) {
    float w = Wt[c * 256 + tid];
    const float4* yr = (const float4*)(smem + c * 48);
    #pragma unroll
    for (int q = 0; q < 12; ++q) {
      float4 v = yr[q];
      acc[4 * q + 0] += w * v.x;
      acc[4 * q + 1] += w * v.y;
      acc[4 * q + 2] += w * v.z;
      acc[4 * q + 3] += w * v.w;
    }
  }

  // ---------------- Phase D: VN-LeakyReLU + store ----------------
  // x = y[tid][j] (this thread's own output row f = tid), d = acc[j]
  const float* xr = smem + tid * 48;
  #pragma unroll
  for (int t = 0; t < TT; ++t) {
    float x0 = xr[t], x1 = xr[16 + t], x2 = xr[32 + t];
    float d0 = acc[t], d1 = acc[16 + t], d2 = acc[32 + t];
    float dot = x0 * d0 + x1 * d1 + x2 * d2;
    float dnsq = d0 * d0 + d1 * d1 + d2 * d2;
    float s = (dot < 0.0f) ? (0.8f * dot / (dnsq + 1e-6f)) : 0.0f;
    acc[t]      = x0 - s * d0;   // overwrite d with output (d already consumed)
    acc[16 + t] = x1 - s * d1;
    acc[32 + t] = x2 - s * d2;
  }
  // out[b][f=tid][i][n0+t], N-contiguous stores
  float* ob = out + ((long)(b * 256 + tid) * 3) * 4096 + n0;
  #pragma unroll
  for (int i = 0; i < 3; ++i) {
    float4* op = (float4*)(ob + (long)i * 4096);
    #pragma unroll
    for (int q = 0; q < 4; ++q)
      op[q] = make_float4(acc[i * 16 + 4 * q + 0], acc[i * 16 + 4 * q + 1],
                          acc[i * 16 + 4 * q + 2], acc[i * 16 + 4 * q + 3]);
  }
}

extern "C" void kernel_launch(void* const* d_in, const int* in_sizes, int n_in,
                              void* d_out, int out_size, void* d_ws, size_t ws_size,
                              hipStream_t stream) {
  const float* X = (const float*)d_in[0];   // [8,4096,128,3]
  const float* J = (const float*)d_in[1];   // [8,4096,128,3,2]
  const float* A = (const float*)d_in[2];   // [256,128]
  const float* B = (const float*)d_in[3];   // [256,128]
  const float* C = (const float*)d_in[4];   // [256,128]
  const float* W = (const float*)d_in[5];   // [256,256]
  // d_in[6] = device scalar, ignored
  float* M3t = (float*)d_ws;                // [128][256]
  float* Wt = M3t + 128 * 256;              // [256][256]
  float* out = (float*)d_out;               // [8,256,3,4096]

  prep_kernel<<<(128 * 256 + 256 * 256) / 256, 256, 0, stream>>>(A, B, C, W, M3t, Wt);
  affine_vnrelu_kernel<<<NBLK, 256, 0, stream>>>(X, J, M3t, Wt, out);
}

// Round 3
// 367.663 us; speedup vs baseline: 1.4054x; 1.4054x over previous
//
#include <hip/hip_runtime.h>

// B=8, N=4096, Din=128, Dout=256. TT=16 tokens/block -> M = 3*16 = 48 rows.
// bf16 3-way split (hi/mid/lo = 24 mantissa bits) + 6 product-class MFMAs
// gives ~fp32-accurate GEMMs on the matrix pipe. The d-path MUST be
// fp32-accurate: out = x - 0.8*(dot/|d|^2)*d amplifies absolute d-noise by
// |x|/|d|, and |d| has a small tail (bf16-only GEMM failed at absmax 22.4).
#define TT 16
#define NBLK 2048
#define LDA 136   // aT row stride (bf16 elems): 128 + 8 pad, 16B-aligned
#define LDY 264   // Yt row stride (bf16 elems): 256 + 8 pad, 16B-aligned

typedef short s16x8 __attribute__((ext_vector_type(8)));   // MFMA A/B frag (8 bf16)
typedef float f32x4 __attribute__((ext_vector_type(4)));   // MFMA C/D frag

__device__ __forceinline__ unsigned short f2bf(float f) {
  union { float f; unsigned u; } v; v.f = f;
  unsigned r = v.u + 0x7FFFu + ((v.u >> 16) & 1u);   // RNE; inputs finite
  return (unsigned short)(r >> 16);
}
__device__ __forceinline__ float bf2f(unsigned short h) {
  union { unsigned u; float f; } v; v.u = ((unsigned)h) << 16;
  return v.f;
}
__device__ __forceinline__ void split3(float x, unsigned short& h,
                                       unsigned short& m, unsigned short& l) {
  h = f2bf(x);
  float r1 = x - bf2f(h);    // exact (Sterbenz region)
  m = f2bf(r1);
  float r2 = r1 - bf2f(m);   // exact
  l = f2bf(r2);
}

__global__ __launch_bounds__(256) void prep_kernel(
    const float* __restrict__ A, const float* __restrict__ Bm,
    const float* __restrict__ C, const float* __restrict__ W,
    unsigned short* __restrict__ M3h, unsigned short* __restrict__ M3m,
    unsigned short* __restrict__ M3l,
    unsigned short* __restrict__ Wh, unsigned short* __restrict__ Wm,
    unsigned short* __restrict__ Wl) {
  int tid = blockIdx.x * 256 + threadIdx.x;
  if (tid < 128 * 256) {
    unsigned short h, m, l;
    split3(A[tid] + Bm[tid] + C[tid], h, m, l);
    M3h[tid] = h; M3m[tid] = m; M3l[tid] = l;
  } else {
    int t2 = tid - 128 * 256;
    unsigned short h, m, l;
    split3(W[t2], h, m, l);
    Wh[t2] = h; Wm[t2] = m; Wl[t2] = l;
  }
}

__global__ __launch_bounds__(256, 2) void affine_vnrelu_mfma(
    const float* __restrict__ X, const float* __restrict__ J,
    const unsigned short* __restrict__ M3h, const unsigned short* __restrict__ M3m,
    const unsigned short* __restrict__ M3l,
    const unsigned short* __restrict__ Wh, const unsigned short* __restrict__ Wm,
    const unsigned short* __restrict__ Wl,
    float* __restrict__ out) {
  // union: phase A/B -> aT splits 3 x [48][LDA] (19584 elems)
  //        phase C/D -> Yt splits 3 x [48][LDY] (38016 elems)
  __shared__ unsigned short smem[3 * 48 * LDY];   // 76032 B -> 2 blocks/CU
  unsigned short* aTh = smem;
  unsigned short* aTm = smem + 48 * LDA;
  unsigned short* aTl = smem + 2 * 48 * LDA;

  const int tid = threadIdx.x;
  const int lane = tid & 63;
  const int w = tid >> 6;          // wave -> f slice [64w, 64w+64)
  const int quad = lane >> 4;
  const int nl = lane & 15;
  const long g0 = (long)blockIdx.x * TT;
  const int b = (int)(g0 >> 12);   // N = 4096
  const int n0 = (int)(g0 & 4095);

  // ---------------- Phase A: Gram-Schmidt + a = R^T X, split to bf16x3 ------
  #pragma unroll
  for (int k = 0; k < 8; ++k) {
    int p = k * 256 + tid;
    int t = p >> 7;
    int dch = p & 127;
    long base = (g0 + t) * 128 + dch;
    const float* Xp = X + base * 3;
    const float* Jp = J + base * 6;
    float x0 = Xp[0], x1 = Xp[1], x2 = Xp[2];
    float j0 = Jp[0], j1 = Jp[1], j2 = Jp[2], j3 = Jp[3], j4 = Jp[4], j5 = Jp[5];
    float c00 = j0, c01 = j2, c02 = j4;
    float a20 = j1, a21 = j3, a22 = j5;
    float n1 = sqrtf(c00 * c00 + c01 * c01 + c02 * c02);
    float inv1 = 1.0f / fmaxf(n1, 1e-12f);
    float b10 = c00 * inv1, b11 = c01 * inv1, b12 = c02 * inv1;
    float pr = b10 * a20 + b11 * a21 + b12 * a22;
    float u0 = a20 - pr * b10, u1 = a21 - pr * b11, u2 = a22 - pr * b12;
    float n2 = sqrtf(u0 * u0 + u1 * u1 + u2 * u2);
    float inv2 = 1.0f / fmaxf(n2, 1e-12f);
    float b20 = u0 * inv2, b21 = u1 * inv2, b22 = u2 * inv2;
    float b30 = b11 * b22 - b12 * b21;
    float b31 = b12 * b20 - b10 * b22;
    float b32 = b10 * b21 - b11 * b20;
    float a0 = b10 * x0 + b11 * x1 + b12 * x2;
    float a1 = b20 * x0 + b21 * x1 + b22 * x2;
    float a2 = b30 * x0 + b31 * x1 + b32 * x2;
    unsigned short h, m, l;
    int r0 = t * LDA + dch;
    split3(a0, h, m, l); aTh[r0] = h; aTm[r0] = m; aTl[r0] = l;
    int r1 = (16 + t) * LDA + dch;
    split3(a1, h, m, l); aTh[r1] = h; aTm[r1] = m; aTl[r1] = l;
    int r2 = (32 + t) * LDA + dch;
    split3(a2, h, m, l); aTh[r2] = h; aTm[r2] = m; aTl[r2] = l;
  }
  __syncthreads();

  const int f0 = w * 64;
  const f32x4 zz = {0.f, 0.f, 0.f, 0.f};

  // ---------------- GEMM1: Y[j][f] = sum_e aT[j][e] * M3[f][e] (split x6) ----
  f32x4 acc1[3][4];
  #pragma unroll
  for (int mt = 0; mt < 3; ++mt)
    #pragma unroll
    for (int nt = 0; nt < 4; ++nt) acc1[mt][nt] = zz;

  #pragma unroll 2
  for (int ks = 0; ks < 4; ++ks) {
    int e0 = ks * 32 + quad * 8;
    s16x8 ah[3], am[3], al[3];
    #pragma unroll
    for (int mt = 0; mt < 3; ++mt) {
      int ao = (mt * 16 + nl) * LDA + e0;
      ah[mt] = *(const s16x8*)(aTh + ao);
      am[mt] = *(const s16x8*)(aTm + ao);
      al[mt] = *(const s16x8*)(aTl + ao);
    }
    #pragma unroll
    for (int nt = 0; nt < 4; ++nt) {
      int bo = (f0 + nt * 16 + nl) * 128 + e0;
      s16x8 bh = *(const s16x8*)(M3h + bo);
      s16x8 bm = *(const s16x8*)(M3m + bo);
      s16x8 bl = *(const s16x8*)(M3l + bo);
      #pragma unroll
      for (int mt = 0; mt < 3; ++mt) {
        f32x4 a = acc1[mt][nt];
        a = __builtin_amdgcn_mfma_f32_16x16x32_bf16(ah[mt], bh, a, 0, 0, 0);
        a = __builtin_amdgcn_mfma_f32_16x16x32_bf16(ah[mt], bm, a, 0, 0, 0);
        a = __builtin_amdgcn_mfma_f32_16x16x32_bf16(am[mt], bh, a, 0, 0, 0);
        a = __builtin_amdgcn_mfma_f32_16x16x32_bf16(ah[mt], bl, a, 0, 0, 0);
        a = __builtin_amdgcn_mfma_f32_16x16x32_bf16(am[mt], bm, a, 0, 0, 0);
        a = __builtin_amdgcn_mfma_f32_16x16x32_bf16(al[mt], bh, a, 0, 0, 0);
        acc1[mt][nt] = a;
      }
    }
  }
  __syncthreads();   // aT region is about to be overwritten by Yt

  // ---------------- stash Y as bf16x3 (exact split of fp32 acc) -------------
  unsigned short* Yth = smem;
  unsigned short* Ytm = smem + 48 * LDY;
  unsigned short* Ytl = smem + 2 * 48 * LDY;
  #pragma unroll
  for (int mt = 0; mt < 3; ++mt)
    #pragma unroll
    for (int nt = 0; nt < 4; ++nt)
      #pragma unroll
      for (int r = 0; r < 4; ++r) {
        unsigned short h, m, l;
        split3(acc1[mt][nt][r], h, m, l);
        int yo = (mt * 16 + quad * 4 + r) * LDY + f0 + nt * 16 + nl;
        Yth[yo] = h; Ytm[yo] = m; Ytl[yo] = l;
      }
  __syncthreads();

  // ---------------- GEMM2: d[j][o] = sum_c Yt[j][c] * W[o][c] (split x6) ----
  f32x4 acc2[3][4];
  #pragma unroll
  for (int mt = 0; mt < 3; ++mt)
    #pragma unroll
    for (int nt = 0; nt < 4; ++nt) acc2[mt][nt] = zz;

  #pragma unroll 2
  for (int ks = 0; ks < 8; ++ks) {
    int c0 = ks * 32 + quad * 8;
    s16x8 ah[3], am[3], al[3];
    #pragma unroll
    for (int mt = 0; mt < 3; ++mt) {
      int ao = (mt * 16 + nl) * LDY + c0;
      ah[mt] = *(const s16x8*)(Yth + ao);
      am[mt] = *(const s16x8*)(Ytm + ao);
      al[mt] = *(const s16x8*)(Ytl + ao);
    }
    #pragma unroll
    for (int nt = 0; nt < 4; ++nt) {
      int bo = (f0 + nt * 16 + nl) * 256 + c0;
      s16x8 bh = *(const s16x8*)(Wh + bo);
      s16x8 bm = *(const s16x8*)(Wm + bo);
      s16x8 bl = *(const s16x8*)(Wl + bo);
      #pragma unroll
      for (int mt = 0; mt < 3; ++mt) {
        f32x4 a = acc2[mt][nt];
        a = __builtin_amdgcn_mfma_f32_16x16x32_bf16(ah[mt], bh, a, 0, 0, 0);
        a = __builtin_amdgcn_mfma_f32_16x16x32_bf16(ah[mt], bm, a, 0, 0, 0);
        a = __builtin_amdgcn_mfma_f32_16x16x32_bf16(am[mt], bh, a, 0, 0, 0);
        a = __builtin_amdgcn_mfma_f32_16x16x32_bf16(ah[mt], bl, a, 0, 0, 0);
        a = __builtin_amdgcn_mfma_f32_16x16x32_bf16(am[mt], bm, a, 0, 0, 0);
        a = __builtin_amdgcn_mfma_f32_16x16x32_bf16(al[mt], bh, a, 0, 0, 0);
        acc2[mt][nt] = a;
      }
    }
  }

  // ---------------- VN-LeakyReLU (lane-local) + float4 stores ---------------
  // lane holds x_i = acc1[i][nt][r], d_i = acc2[i][nt][r] at the SAME (f, t):
  // f = f0 + nt*16 + nl, t = quad*4 + r.
  #pragma unroll
  for (int nt = 0; nt < 4; ++nt) {
    int f = f0 + nt * 16 + nl;
    float* ob = out + ((long)(b * 256 + f) * 3) * 4096 + n0 + quad * 4;
    float o[3][4];
    #pragma unroll
    for (int r = 0; r < 4; ++r) {
      float x0 = acc1[0][nt][r], x1 = acc1[1][nt][r], x2 = acc1[2][nt][r];
      float d0 = acc2[0][nt][r], d1 = acc2[1][nt][r], d2 = acc2[2][nt][r];
      float dot = x0 * d0 + x1 * d1 + x2 * d2;
      float dn = d0 * d0 + d1 * d1 + d2 * d2;
      float s = (dot < 0.0f) ? (0.8f * dot / (dn + 1e-6f)) : 0.0f;
      o[0][r] = x0 - s * d0;
      o[1][r] = x1 - s * d1;
      o[2][r] = x2 - s * d2;
    }
    #pragma unroll
    for (int i = 0; i < 3; ++i)
      *(float4*)(ob + ((long)i * 4096)) = make_float4(o[i][0], o[i][1], o[i][2], o[i][3]);
  }
}

extern "C" void kernel_launch(void* const* d_in, const int* in_sizes, int n_in,
                              void* d_out, int out_size, void* d_ws, size_t ws_size,
                              hipStream_t stream) {
  const float* X = (const float*)d_in[0];   // [8,4096,128,3]
  const float* J = (const float*)d_in[1];   // [8,4096,128,3,2]
  const float* A = (const float*)d_in[2];   // [256,128]
  const float* B = (const float*)d_in[3];   // [256,128]
  const float* C = (const float*)d_in[4];   // [256,128]
  const float* W = (const float*)d_in[5];   // [256,256]
  unsigned short* M3h = (unsigned short*)d_ws;        // 3 x 32768 bf16
  unsigned short* M3m = M3h + 128 * 256;
  unsigned short* M3l = M3m + 128 * 256;
  unsigned short* Wh  = M3l + 128 * 256;              // 3 x 65536 bf16
  unsigned short* Wm  = Wh + 256 * 256;
  unsigned short* Wl  = Wm + 256 * 256;               // total 576 KB of ws
  float* out = (float*)d_out;               // [8,256,3,4096]

  prep_kernel<<<(128 * 256 + 256 * 256) / 256, 256, 0, stream>>>(
      A, B, C, W, M3h, M3m, M3l, Wh, Wm, Wl);
  affine_vnrelu_mfma<<<NBLK, 256, 0, stream>>>(
      X, J, M3h, M3m, M3l, Wh, Wm, Wl, out);
}

// Round 4
// 328.515 us; speedup vs baseline: 1.5729x; 1.1192x over previous
//
#include <hip/hip_runtime.h>

// B=8, N=4096, Din=128, Dout=256. TT=16 tokens/block -> M = 3*16 = 48 rows.
// bf16 2-way split (hi/mid = 16 mantissa bits) + 3 product-class MFMAs
// (hh+hm+mh; omitted mm ~ 2^-16 relative = representation error).
// Error model: bf16-only (2^-8) failed at absmax 22.4; error is linear in the
// split noise -> 2-way lands ~0.2 over the 0.25 fp32 floor, vs threshold 2.42.
// The d-path needs this accuracy: out = x - 0.8*(dot/|d|^2)*d amplifies
// absolute d-noise by |x|/|d| and |d| has a small tail over 8.4M samples.
#define TT 16
#define NBLK 2048
#define LDA 136   // aT row stride (bf16 elems): 128 + 8 pad, 16B-aligned
#define LDY 264   // Yt row stride (bf16 elems): 256 + 8 pad, 16B-aligned

typedef short s16x8 __attribute__((ext_vector_type(8)));   // MFMA A/B frag (8 bf16)
typedef float f32x4 __attribute__((ext_vector_type(4)));   // MFMA C/D frag

__device__ __forceinline__ unsigned short f2bf(float f) {
  union { float f; unsigned u; } v; v.f = f;
  unsigned r = v.u + 0x7FFFu + ((v.u >> 16) & 1u);   // RNE; inputs finite
  return (unsigned short)(r >> 16);
}
__device__ __forceinline__ float bf2f(unsigned short h) {
  union { unsigned u; float f; } v; v.u = ((unsigned)h) << 16;
  return v.f;
}
__device__ __forceinline__ void split2(float x, unsigned short& h, unsigned short& m) {
  h = f2bf(x);
  m = f2bf(x - bf2f(h));   // subtraction exact (binary-split argument)
}

__global__ __launch_bounds__(256) void prep_kernel(
    const float* __restrict__ A, const float* __restrict__ Bm,
    const float* __restrict__ C, const float* __restrict__ W,
    unsigned short* __restrict__ M3h, unsigned short* __restrict__ M3m,
    unsigned short* __restrict__ Wh, unsigned short* __restrict__ Wm) {
  int tid = blockIdx.x * 256 + threadIdx.x;
  if (tid < 128 * 256) {
    unsigned short h, m;
    split2(A[tid] + Bm[tid] + C[tid], h, m);
    M3h[tid] = h; M3m[tid] = m;
  } else {
    int t2 = tid - 128 * 256;
    unsigned short h, m;
    split2(W[t2], h, m);
    Wh[t2] = h; Wm[t2] = m;
  }
}

__global__ __launch_bounds__(256, 3) void affine_vnrelu_mfma(
    const float* __restrict__ X, const float* __restrict__ J,
    const unsigned short* __restrict__ M3h, const unsigned short* __restrict__ M3m,
    const unsigned short* __restrict__ Wh, const unsigned short* __restrict__ Wm,
    float* __restrict__ out) {
  // union: phase A/B -> aT splits 2 x [48][LDA] (13056 elems)
  //        phase C/D -> Yt splits 2 x [48][LDY] (25344 elems)
  __shared__ unsigned short smem[2 * 48 * LDY];   // 50688 B -> 3 blocks/CU
  unsigned short* aTh = smem;
  unsigned short* aTm = smem + 48 * LDA;

  const int tid = threadIdx.x;
  const int lane = tid & 63;
  const int w = tid >> 6;          // wave -> f slice [64w, 64w+64)
  const int quad = lane >> 4;
  const int nl = lane & 15;
  const long g0 = (long)blockIdx.x * TT;
  const int b = (int)(g0 >> 12);   // N = 4096
  const int n0 = (int)(g0 & 4095);

  // ---------------- Phase A: Gram-Schmidt + a = R^T X, split to bf16x2 ------
  #pragma unroll
  for (int k = 0; k < 8; ++k) {
    int p = k * 256 + tid;
    int t = p >> 7;
    int dch = p & 127;
    long base = (g0 + t) * 128 + dch;
    const float* Xp = X + base * 3;
    const float* Jp = J + base * 6;
    float x0 = Xp[0], x1 = Xp[1], x2 = Xp[2];
    float j0 = Jp[0], j1 = Jp[1], j2 = Jp[2], j3 = Jp[3], j4 = Jp[4], j5 = Jp[5];
    float c00 = j0, c01 = j2, c02 = j4;          // col0 of the 3x2
    float a20 = j1, a21 = j3, a22 = j5;          // col1
    float n1 = sqrtf(c00 * c00 + c01 * c01 + c02 * c02);
    float inv1 = 1.0f / fmaxf(n1, 1e-12f);
    float b10 = c00 * inv1, b11 = c01 * inv1, b12 = c02 * inv1;
    float pr = b10 * a20 + b11 * a21 + b12 * a22;
    float u0 = a20 - pr * b10, u1 = a21 - pr * b11, u2 = a22 - pr * b12;
    float n2 = sqrtf(u0 * u0 + u1 * u1 + u2 * u2);
    float inv2 = 1.0f / fmaxf(n2, 1e-12f);
    float b20 = u0 * inv2, b21 = u1 * inv2, b22 = u2 * inv2;
    float b30 = b11 * b22 - b12 * b21;
    float b31 = b12 * b20 - b10 * b22;
    float b32 = b10 * b21 - b11 * b20;
    unsigned short h, m;
    int r0 = t * LDA + dch;
    split2(b10 * x0 + b11 * x1 + b12 * x2, h, m); aTh[r0] = h; aTm[r0] = m;
    int r1 = (16 + t) * LDA + dch;
    split2(b20 * x0 + b21 * x1 + b22 * x2, h, m); aTh[r1] = h; aTm[r1] = m;
    int r2 = (32 + t) * LDA + dch;
    split2(b30 * x0 + b31 * x1 + b32 * x2, h, m); aTh[r2] = h; aTm[r2] = m;
  }
  __syncthreads();

  const int f0 = w * 64;
  const f32x4 zz = {0.f, 0.f, 0.f, 0.f};

  // ---------------- GEMM1: Y[j][f] = sum_e aT[j][e] * M3[f][e] (split x3) ----
  f32x4 acc1[3][4];
  #pragma unroll
  for (int mt = 0; mt < 3; ++mt)
    #pragma unroll
    for (int nt = 0; nt < 4; ++nt) acc1[mt][nt] = zz;

  #pragma unroll 2
  for (int ks = 0; ks < 4; ++ks) {
    int e0 = ks * 32 + quad * 8;
    s16x8 ah[3], am[3];
    #pragma unroll
    for (int mt = 0; mt < 3; ++mt) {
      int ao = (mt * 16 + nl) * LDA + e0;
      ah[mt] = *(const s16x8*)(aTh + ao);
      am[mt] = *(const s16x8*)(aTm + ao);
    }
    #pragma unroll
    for (int nt = 0; nt < 4; ++nt) {
      int bo = (f0 + nt * 16 + nl) * 128 + e0;
      s16x8 bh = *(const s16x8*)(M3h + bo);
      s16x8 bm = *(const s16x8*)(M3m + bo);
      #pragma unroll
      for (int mt = 0; mt < 3; ++mt) {
        f32x4 a = acc1[mt][nt];
        a = __builtin_amdgcn_mfma_f32_16x16x32_bf16(ah[mt], bh, a, 0, 0, 0);
        a = __builtin_amdgcn_mfma_f32_16x16x32_bf16(ah[mt], bm, a, 0, 0, 0);
        a = __builtin_amdgcn_mfma_f32_16x16x32_bf16(am[mt], bh, a, 0, 0, 0);
        acc1[mt][nt] = a;
      }
    }
  }
  __syncthreads();   // aT region is about to be overwritten by Yt

  // ---------------- stash Y as bf16x2 (exact split of fp32 acc) -------------
  unsigned short* Yth = smem;
  unsigned short* Ytm = smem + 48 * LDY;
  #pragma unroll
  for (int mt = 0; mt < 3; ++mt)
    #pragma unroll
    for (int nt = 0; nt < 4; ++nt)
      #pragma unroll
      for (int r = 0; r < 4; ++r) {
        unsigned short h, m;
        split2(acc1[mt][nt][r], h, m);
        int yo = (mt * 16 + quad * 4 + r) * LDY + f0 + nt * 16 + nl;
        Yth[yo] = h; Ytm[yo] = m;
      }
  __syncthreads();

  // ---------------- GEMM2: d[j][o] = sum_c Yt[j][c] * W[o][c] (split x3) ----
  f32x4 acc2[3][4];
  #pragma unroll
  for (int mt = 0; mt < 3; ++mt)
    #pragma unroll
    for (int nt = 0; nt < 4; ++nt) acc2[mt][nt] = zz;

  #pragma unroll 2
  for (int ks = 0; ks < 8; ++ks) {
    int c0 = ks * 32 + quad * 8;
    s16x8 ah[3], am[3];
    #pragma unroll
    for (int mt = 0; mt < 3; ++mt) {
      int ao = (mt * 16 + nl) * LDY + c0;
      ah[mt] = *(const s16x8*)(Yth + ao);
      am[mt] = *(const s16x8*)(Ytm + ao);
    }
    #pragma unroll
    for (int nt = 0; nt < 4; ++nt) {
      int bo = (f0 + nt * 16 + nl) * 256 + c0;
      s16x8 bh = *(const s16x8*)(Wh + bo);
      s16x8 bm = *(const s16x8*)(Wm + bo);
      #pragma unroll
      for (int mt = 0; mt < 3; ++mt) {
        f32x4 a = acc2[mt][nt];
        a = __builtin_amdgcn_mfma_f32_16x16x32_bf16(ah[mt], bh, a, 0, 0, 0);
        a = __builtin_amdgcn_mfma_f32_16x16x32_bf16(ah[mt], bm, a, 0, 0, 0);
        a = __builtin_amdgcn_mfma_f32_16x16x32_bf16(am[mt], bh, a, 0, 0, 0);
        acc2[mt][nt] = a;
      }
    }
  }

  // ---------------- VN-LeakyReLU (lane-local) + float4 stores ---------------
  // lane holds x_i = acc1[i][nt][r], d_i = acc2[i][nt][r] at the SAME (f, t):
  // f = f0 + nt*16 + nl, t = quad*4 + r.
  #pragma unroll
  for (int nt = 0; nt < 4; ++nt) {
    int f = f0 + nt * 16 + nl;
    float* ob = out + ((long)(b * 256 + f) * 3) * 4096 + n0 + quad * 4;
    float o[3][4];
    #pragma unroll
    for (int r = 0; r < 4; ++r) {
      float x0 = acc1[0][nt][r], x1 = acc1[1][nt][r], x2 = acc1[2][nt][r];
      float d0 = acc2[0][nt][r], d1 = acc2[1][nt][r], d2 = acc2[2][nt][r];
      float dot = x0 * d0 + x1 * d1 + x2 * d2;
      float dn = d0 * d0 + d1 * d1 + d2 * d2;
      float s = (dot < 0.0f) ? (0.8f * dot / (dn + 1e-6f)) : 0.0f;
      o[0][r] = x0 - s * d0;
      o[1][r] = x1 - s * d1;
      o[2][r] = x2 - s * d2;
    }
    #pragma unroll
    for (int i = 0; i < 3; ++i)
      *(float4*)(ob + ((long)i * 4096)) = make_float4(o[i][0], o[i][1], o[i][2], o[i][3]);
  }
}

extern "C" void kernel_launch(void* const* d_in, const int* in_sizes, int n_in,
                              void* d_out, int out_size, void* d_ws, size_t ws_size,
                              hipStream_t stream) {
  const float* X = (const float*)d_in[0];   // [8,4096,128,3]
  const float* J = (const float*)d_in[1];   // [8,4096,128,3,2]
  const float* A = (const float*)d_in[2];   // [256,128]
  const float* B = (const float*)d_in[3];   // [256,128]
  const float* C = (const float*)d_in[4];   // [256,128]
  const float* W = (const float*)d_in[5];   // [256,256]
  unsigned short* M3h = (unsigned short*)d_ws;        // 2 x 32768 bf16
  unsigned short* M3m = M3h + 128 * 256;
  unsigned short* Wh  = M3m + 128 * 256;              // 2 x 65536 bf16
  unsigned short* Wm  = Wh + 256 * 256;               // total 384 KB of ws
  float* out = (float*)d_out;               // [8,256,3,4096]

  prep_kernel<<<(128 * 256 + 256 * 256) / 256, 256, 0, stream>>>(
      A, B, C, W, M3h, M3m, Wh, Wm);
  affine_vnrelu_mfma<<<NBLK, 256, 0, stream>>>(
      X, J, M3h, M3m, Wh, Wm, out);
}

// Round 5
// 306.464 us; speedup vs baseline: 1.6861x; 1.0720x over previous
//
#include <hip/hip_runtime.h>

// B=8, N=4096, Din=128, Dout=256. TT=16 tokens/block -> M = 3*16 = 48 rows.
// bf16 2-way split (hi/mid) + 3 product-class MFMAs = ~24-bit GEMMs (validated:
// absmax 0.5 vs threshold 2.42; bf16-only fails at 22.4 via |x|/|d| noise
// amplification in the VN-LeakyReLU projection).
// R5: occupancy was REGISTER-bound (VGPR 84 + AGPR 96 ~ 180 -> 2 waves/SIMD).
// Split f across 8 waves (512-thr blocks, nt=2): acc 96->48 regs, target
// 4 waves/SIMD via __launch_bounds__(512,4).
#define TT 16
#define NBLK 2048
#define LDA 136   // aT row stride (bf16): 128 + 8 pad, 16B-aligned rows
#define LDY 264   // Yt row stride (bf16): 256 + 8 pad, 16B-aligned rows

typedef short s16x8 __attribute__((ext_vector_type(8)));
typedef float f32x4 __attribute__((ext_vector_type(4)));

__device__ __forceinline__ unsigned short f2bf(float f) {
  union { float f; unsigned u; } v; v.f = f;
  unsigned r = v.u + 0x7FFFu + ((v.u >> 16) & 1u);   // RNE; inputs finite
  return (unsigned short)(r >> 16);
}
__device__ __forceinline__ float bf2f(unsigned short h) {
  union { unsigned u; float f; } v; v.u = ((unsigned)h) << 16;
  return v.f;
}
__device__ __forceinline__ void split2(float x, unsigned short& h, unsigned short& m) {
  h = f2bf(x);
  m = f2bf(x - bf2f(h));   // exact subtraction
}

__global__ __launch_bounds__(256) void prep_kernel(
    const float* __restrict__ A, const float* __restrict__ Bm,
    const float* __restrict__ C, const float* __restrict__ W,
    unsigned short* __restrict__ M3h, unsigned short* __restrict__ M3m,
    unsigned short* __restrict__ Wh, unsigned short* __restrict__ Wm) {
  int tid = blockIdx.x * 256 + threadIdx.x;
  if (tid < 128 * 256) {
    unsigned short h, m;
    split2(A[tid] + Bm[tid] + C[tid], h, m);
    M3h[tid] = h; M3m[tid] = m;
  } else {
    int t2 = tid - 128 * 256;
    unsigned short h, m;
    split2(W[t2], h, m);
    Wh[t2] = h; Wm[t2] = m;
  }
}

__global__ __launch_bounds__(512, 4) void affine_vnrelu_mfma(
    const float* __restrict__ X, const float* __restrict__ J,
    const unsigned short* __restrict__ M3h, const unsigned short* __restrict__ M3m,
    const unsigned short* __restrict__ Wh, const unsigned short* __restrict__ Wm,
    float* __restrict__ out) {
  // union: phase A/B -> aT splits 2 x [48][LDA]; phase C/D -> Yt 2 x [48][LDY]
  __shared__ unsigned short smem[2 * 48 * LDY];   // 50688 B
  unsigned short* aTh = smem;
  unsigned short* aTm = smem + 48 * LDA;

  const int tid = threadIdx.x;
  const int lane = tid & 63;
  const int w = tid >> 6;          // wave 0..7 -> f slice [32w, 32w+32)
  const int quad = lane >> 4;
  const int nl = lane & 15;
  const long g0 = (long)blockIdx.x * TT;
  const int b = (int)(g0 >> 12);   // N = 4096
  const int n0 = (int)(g0 & 4095);

  // ---------------- Phase A: Gram-Schmidt + a = R^T X, split to bf16x2 ------
  #pragma unroll
  for (int k = 0; k < 4; ++k) {
    int p = k * 512 + tid;
    int t = p >> 7;
    int dch = p & 127;
    long base = (g0 + t) * 128 + dch;
    const float* Xp = X + base * 3;
    const float* Jp = J + base * 6;
    float x0 = Xp[0], x1 = Xp[1], x2 = Xp[2];
    float j0 = Jp[0], j1 = Jp[1], j2 = Jp[2], j3 = Jp[3], j4 = Jp[4], j5 = Jp[5];
    float c00 = j0, c01 = j2, c02 = j4;          // col0 of the 3x2
    float a20 = j1, a21 = j3, a22 = j5;          // col1
    float n1 = sqrtf(c00 * c00 + c01 * c01 + c02 * c02);
    float inv1 = 1.0f / fmaxf(n1, 1e-12f);
    float b10 = c00 * inv1, b11 = c01 * inv1, b12 = c02 * inv1;
    float pr = b10 * a20 + b11 * a21 + b12 * a22;
    float u0 = a20 - pr * b10, u1 = a21 - pr * b11, u2 = a22 - pr * b12;
    float n2 = sqrtf(u0 * u0 + u1 * u1 + u2 * u2);
    float inv2 = 1.0f / fmaxf(n2, 1e-12f);
    float b20 = u0 * inv2, b21 = u1 * inv2, b22 = u2 * inv2;
    float b30 = b11 * b22 - b12 * b21;
    float b31 = b12 * b20 - b10 * b22;
    float b32 = b10 * b21 - b11 * b20;
    unsigned short h, m;
    int r0 = t * LDA + dch;
    split2(b10 * x0 + b11 * x1 + b12 * x2, h, m); aTh[r0] = h; aTm[r0] = m;
    int r1 = (16 + t) * LDA + dch;
    split2(b20 * x0 + b21 * x1 + b22 * x2, h, m); aTh[r1] = h; aTm[r1] = m;
    int r2 = (32 + t) * LDA + dch;
    split2(b30 * x0 + b31 * x1 + b32 * x2, h, m); aTh[r2] = h; aTm[r2] = m;
  }
  __syncthreads();

  const int f0 = w * 32;
  const f32x4 zz = {0.f, 0.f, 0.f, 0.f};

  // ---------------- GEMM1: Y[j][f] = sum_e aT[j][e] * M3[f][e] (split x3) ----
  f32x4 acc1[3][2];
  #pragma unroll
  for (int mt = 0; mt < 3; ++mt)
    #pragma unroll
    for (int nt = 0; nt < 2; ++nt) acc1[mt][nt] = zz;

  #pragma unroll 2
  for (int ks = 0; ks < 4; ++ks) {
    int e0 = ks * 32 + quad * 8;
    s16x8 bh[2], bm[2];
    #pragma unroll
    for (int nt = 0; nt < 2; ++nt) {
      int bo = (f0 + nt * 16 + nl) * 128 + e0;
      bh[nt] = *(const s16x8*)(M3h + bo);
      bm[nt] = *(const s16x8*)(M3m + bo);
    }
    #pragma unroll
    for (int mt = 0; mt < 3; ++mt) {
      int ao = (mt * 16 + nl) * LDA + e0;
      s16x8 ah = *(const s16x8*)(aTh + ao);
      s16x8 am = *(const s16x8*)(aTm + ao);
      #pragma unroll
      for (int nt = 0; nt < 2; ++nt) {
        f32x4 a = acc1[mt][nt];
        a = __builtin_amdgcn_mfma_f32_16x16x32_bf16(ah, bh[nt], a, 0, 0, 0);
        a = __builtin_amdgcn_mfma_f32_16x16x32_bf16(ah, bm[nt], a, 0, 0, 0);
        a = __builtin_amdgcn_mfma_f32_16x16x32_bf16(am, bh[nt], a, 0, 0, 0);
        acc1[mt][nt] = a;
      }
    }
  }
  __syncthreads();   // aT region about to be overwritten by Yt

  // ---------------- stash Y as bf16x2 (exact split of fp32 acc) -------------
  unsigned short* Yth = smem;
  unsigned short* Ytm = smem + 48 * LDY;
  #pragma unroll
  for (int mt = 0; mt < 3; ++mt)
    #pragma unroll
    for (int nt = 0; nt < 2; ++nt)
      #pragma unroll
      for (int r = 0; r < 4; ++r) {
        unsigned short h, m;
        split2(acc1[mt][nt][r], h, m);
        int yo = (mt * 16 + quad * 4 + r) * LDY + f0 + nt * 16 + nl;
        Yth[yo] = h; Ytm[yo] = m;
      }
  __syncthreads();

  // ---------------- GEMM2: d[j][o] = sum_c Yt[j][c] * W[o][c] (split x3) ----
  f32x4 acc2[3][2];
  #pragma unroll
  for (int mt = 0; mt < 3; ++mt)
    #pragma unroll
    for (int nt = 0; nt < 2; ++nt) acc2[mt][nt] = zz;

  #pragma unroll 2
  for (int ks = 0; ks < 8; ++ks) {
    int c0 = ks * 32 + quad * 8;
    s16x8 bh[2], bm[2];
    #pragma unroll
    for (int nt = 0; nt < 2; ++nt) {
      int bo = (f0 + nt * 16 + nl) * 256 + c0;
      bh[nt] = *(const s16x8*)(Wh + bo);
      bm[nt] = *(const s16x8*)(Wm + bo);
    }
    #pragma unroll
    for (int mt = 0; mt < 3; ++mt) {
      int ao = (mt * 16 + nl) * LDY + c0;
      s16x8 ah = *(const s16x8*)(Yth + ao);
      s16x8 am = *(const s16x8*)(Ytm + ao);
      #pragma unroll
      for (int nt = 0; nt < 2; ++nt) {
        f32x4 a = acc2[mt][nt];
        a = __builtin_amdgcn_mfma_f32_16x16x32_bf16(ah, bh[nt], a, 0, 0, 0);
        a = __builtin_amdgcn_mfma_f32_16x16x32_bf16(ah, bm[nt], a, 0, 0, 0);
        a = __builtin_amdgcn_mfma_f32_16x16x32_bf16(am, bh[nt], a, 0, 0, 0);
        acc2[mt][nt] = a;
      }
    }
  }

  // ---------------- VN-LeakyReLU (lane-local) + float4 stores ---------------
  // lane holds x_i = acc1[i][nt][r], d_i = acc2[i][nt][r] at the SAME (f, t):
  // f = f0 + nt*16 + nl, t = quad*4 + r.
  #pragma unroll
  for (int nt = 0; nt < 2; ++nt) {
    int f = f0 + nt * 16 + nl;
    float* ob = out + ((long)(b * 256 + f) * 3) * 4096 + n0 + quad * 4;
    float o[3][4];
    #pragma unroll
    for (int r = 0; r < 4; ++r) {
      float x0 = acc1[0][nt][r], x1 = acc1[1][nt][r], x2 = acc1[2][nt][r];
      float d0 = acc2[0][nt][r], d1 = acc2[1][nt][r], d2 = acc2[2][nt][r];
      float dot = x0 * d0 + x1 * d1 + x2 * d2;
      float dn = d0 * d0 + d1 * d1 + d2 * d2;
      float s = (dot < 0.0f) ? (0.8f * dot / (dn + 1e-6f)) : 0.0f;
      o[0][r] = x0 - s * d0;
      o[1][r] = x1 - s * d1;
      o[2][r] = x2 - s * d2;
    }
    #pragma unroll
    for (int i = 0; i < 3; ++i)
      *(float4*)(ob + ((long)i * 4096)) = make_float4(o[i][0], o[i][1], o[i][2], o[i][3]);
  }
}

extern "C" void kernel_launch(void* const* d_in, const int* in_sizes, int n_in,
                              void* d_out, int out_size, void* d_ws, size_t ws_size,
                              hipStream_t stream) {
  const float* X = (const float*)d_in[0];   // [8,4096,128,3]
  const float* J = (const float*)d_in[1];   // [8,4096,128,3,2]
  const float* A = (const float*)d_in[2];   // [256,128]
  const float* B = (const float*)d_in[3];   // [256,128]
  const float* C = (const float*)d_in[4];   // [256,128]
  const float* W = (const float*)d_in[5];   // [256,256]
  unsigned short* M3h = (unsigned short*)d_ws;        // 2 x 32768 bf16
  unsigned short* M3m = M3h + 128 * 256;
  unsigned short* Wh  = M3m + 128 * 256;              // 2 x 65536 bf16
  unsigned short* Wm  = Wh + 256 * 256;               // total 384 KB of ws
  float* out = (float*)d_out;               // [8,256,3,4096]

  prep_kernel<<<(128 * 256 + 256 * 256) / 256, 256, 0, stream>>>(
      A, B, C, W, M3h, M3m, Wh, Wm);
  affine_vnrelu_mfma<<<NBLK, 512, 0, stream>>>(
      X, J, M3h, M3m, Wh, Wm, out);
}